// Round 9
// baseline (520.056 us; speedup 1.0000x reference)
//
#include <hip/hip_runtime.h>
#include <math.h>

// CharacterBertCharacterCNN — Round 9 (ABLATION + coalesced-B fix)
// Diagnosis round: R7/R8 theories failed (dur flat at ~189us, VGPR=60).
// Launch order: wpack, wpack2, conv_any<0> (1/4 grid, R8 replica),
// conv_any<1> (1/4 grid, NO B-loads -> isolates B-path stall),
// conv_any<2> == real conv (full grid, COALESCED B layout), GEMM chain.
// Diag dispatches write garbage to t0h tokens 0-1023; the full-grid real
// conv overwrites all of t0h before any consumer. rocprof per-dispatch rows
// give within-run A/B.
//
// ws layout (bytes):
//   t0h      @ 0         : 16,777,216
//   t1h      @ 16777216  : 16,777,216
//   wbuf     @ 33554432  : 16,777,216   (w0t, then w1t, then pwt)
//   bias_all @ 50331648  : 8,192
//   Wp       @ 50339840  : 438,272     (old strided layout, diag0)
//   Wp2      @ 50778112  : 438,272     (coalesced layout, real)
//   total ~51.2 MB

#define NTOK 4096
#define NCHAR 50
#define EMB 16
#define TF 2048
#define HID 768
#define BK 64       // GEMM k-tile

typedef float f32x4 __attribute__((ext_vector_type(4)));
typedef _Float16 f16x8 __attribute__((ext_vector_type(8)));
typedef _Float16 half_t;

__device__ __forceinline__ void gl_lds16(const void* g, void* l) {
  __builtin_amdgcn_global_load_lds(
      (const __attribute__((address_space(1))) void*)g,
      (__attribute__((address_space(3))) void*)l, 16, 0, 0);
}

// ------------------------------------------------------- weight packing ----
// OLD layout (diag0): Wp[c][k], k=j*16+i, kpad per width, zero pad.
// Width bases (halfs): W1@0 W2@1024 W3@2048 W4@6144 W5@14336 W6@38912
// W7@88064, total 219136. (Same bases for both layouts.)
__global__ __launch_bounds__(256) void wpack_kernel(
    const float* __restrict__ w0, const float* __restrict__ w1,
    const float* __restrict__ w2, const float* __restrict__ w3,
    const float* __restrict__ w4, const float* __restrict__ w5,
    const float* __restrict__ w6,
    const float* __restrict__ b0, const float* __restrict__ b1,
    const float* __restrict__ b2, const float* __restrict__ b3,
    const float* __restrict__ b4, const float* __restrict__ b5,
    const float* __restrict__ b6,
    half_t* __restrict__ Wp, float* __restrict__ bias_all) {
  const int idx = blockIdx.x * 256 + threadIdx.x;
  if (idx < 219136) {
    int c, k, w; const float* src;
    if (idx < 1024)       { c = idx >> 5;             k = idx & 31;          w = 1; src = w0; }
    else if (idx < 2048)  { const int t = idx - 1024;  c = t >> 5; k = t & 31;  w = 2; src = w1; }
    else if (idx < 6144)  { const int t = idx - 2048;  c = t >> 6; k = t & 63;  w = 3; src = w2; }
    else if (idx < 14336) { const int t = idx - 6144;  c = t >> 6; k = t & 63;  w = 4; src = w3; }
    else if (idx < 38912) { const int t = idx - 14336; c = t / 96; k = t % 96;  w = 5; src = w4; }
    else if (idx < 88064) { const int t = idx - 38912; c = t / 96; k = t % 96;  w = 6; src = w5; }
    else                  { const int t = idx - 88064; c = t >> 7; k = t & 127; w = 7; src = w6; }
    const int j = k >> 4, i = k & 15;
    Wp[idx] = (half_t)((j < w) ? src[(c * EMB + i) * w + j] : 0.f);
  } else if (idx < 219136 + 2048) {
    const int c = idx - 219136;
    float v;
    if (c < 32)        v = b0[c];
    else if (c < 64)   v = b1[c - 32];
    else if (c < 128)  v = b2[c - 64];
    else if (c < 256)  v = b3[c - 128];
    else if (c < 512)  v = b4[c - 256];
    else if (c < 1024) v = b5[c - 512];
    else               v = b6[c - 1024];
    bias_all[c] = v;
  }
}

// COALESCED layout (real): per (width, nt, kk) a 512-half block ordered
// [lane][e]: half index = base + ((nt*KKw + kk)*64 + lane)*8 + e, where
// lane = l16*16 + l15 maps to channel nt*16+l15, k = kk*32 + l16*8 + e.
// A wave's fragment load is then lane*16B contiguous -> one 1KB burst.
__global__ __launch_bounds__(256) void wpack2_kernel(
    const float* __restrict__ w0, const float* __restrict__ w1,
    const float* __restrict__ w2, const float* __restrict__ w3,
    const float* __restrict__ w4, const float* __restrict__ w5,
    const float* __restrict__ w6, half_t* __restrict__ Wp2) {
  const int idx = blockIdx.x * 256 + threadIdx.x;
  if (idx >= 219136) return;
  int t, w, kpad; const float* src;
  if (idx < 1024)       { t = idx;          w = 1; kpad = 32;  src = w0; }
  else if (idx < 2048)  { t = idx - 1024;   w = 2; kpad = 32;  src = w1; }
  else if (idx < 6144)  { t = idx - 2048;   w = 3; kpad = 64;  src = w2; }
  else if (idx < 14336) { t = idx - 6144;   w = 4; kpad = 64;  src = w3; }
  else if (idx < 38912) { t = idx - 14336;  w = 5; kpad = 96;  src = w4; }
  else if (idx < 88064) { t = idx - 38912;  w = 6; kpad = 96;  src = w5; }
  else                  { t = idx - 88064;  w = 7; kpad = 128; src = w6; }
  const int e = t & 7, lane = (t >> 3) & 63, blk = t >> 9;
  const int KKw = kpad >> 5;
  const int kk = blk % KKw, nt = blk / KKw;
  const int c = nt * 16 + (lane & 15);
  const int k = kk * 32 + (lane >> 4) * 8 + e;
  const int j = k >> 4, i = k & 15;
  Wp2[idx] = (half_t)((j < w) ? src[(c * EMB + i) * w + j] : 0.f);
}

// ---------------------------------------------------------------- conv ----
// V=0: old strided B loads (R8 replica). V=1: NO B loads (asm-pinned zero
// b; MFMA/epilogue/output kept live -> isolates B-path cost). V=2: coalesced
// B loads from Wp2. Everything else identical across variants.

template<int V, int MT, int KK, int NT, int L>
__device__ __forceinline__ void conv_worker(
    const char* myemb, float* pm,
    const half_t* __restrict__ W,          // width-region base (layout per V)
    const float* __restrict__ bias, half_t* __restrict__ outp,
    int kpad, int lane) {
  constexpr int S = NT * 16 + 8;
  const int l15 = lane & 15, l16 = lane >> 4;

  f16x8 a[MT][KK];
#pragma unroll
  for (int m = 0; m < MT; ++m)
#pragma unroll
    for (int kk = 0; kk < KK; ++kk) {
      const int row = m * 16 + l15 + 2 * kk + (l16 >> 1);
      a[m][kk] = *(const f16x8*)(myemb + row * 48 + (l16 & 1) * 16);
    }
#pragma unroll
  for (int m = 0; m < MT; ++m)
#pragma unroll
    for (int kk = 0; kk < KK; ++kk)
      asm volatile("" : "+v"(a[m][kk]));

  const half_t* bpo = W + (size_t)l15 * kpad + l16 * 8;   // V0 strided
  const half_t* bpc = W + (size_t)lane * 8;               // V2 coalesced
  const size_t ntstep = (size_t)16 * kpad;

  auto loadB = [&](int nt, int kk) -> f16x8 {
    if constexpr (V == 0)
      return *(const f16x8*)(bpo + (size_t)nt * ntstep + kk * 32);
    else
      return *(const f16x8*)(bpc + (((size_t)nt * KK + kk) << 9));
  };

  auto group = [&](int nt, const f16x8 (&b)[KK]) {
    f32x4 acc[MT];
#pragma unroll
    for (int m = 0; m < MT; ++m) acc[m] = (f32x4){0.f, 0.f, 0.f, 0.f};
#pragma unroll
    for (int kk = 0; kk < KK; ++kk)
#pragma unroll
      for (int m = 0; m < MT; ++m)
        acc[m] = __builtin_amdgcn_mfma_f32_16x16x32_f16(a[m][kk], b[kk], acc[m], 0, 0, 0);
    float t[MT * 4];
#pragma unroll
    for (int m = 0; m < MT; ++m)
#pragma unroll
      for (int j = 0; j < 4; ++j) {
        const int pos = m * 16 + l16 * 4 + j;
        if ((m * 16 + 15) < L)
          t[m * 4 + j] = acc[m][j];
        else
          t[m * 4 + j] = (pos < L) ? acc[m][j] : -1e30f;
      }
#pragma unroll
    for (int s = 1; s < MT * 4; s *= 2)
#pragma unroll
      for (int i = 0; i + s < MT * 4; i += 2 * s)
        t[i] = fmaxf(t[i], t[i + s]);
    pm[l16 * S + nt * 16 + l15] = t[0];
  };

  if constexpr (V == 1) {
    f16x8 bz[KK];
#pragma unroll
    for (int kk = 0; kk < KK; ++kk) {
#pragma unroll
      for (int q = 0; q < 8; ++q) bz[kk][q] = (half_t)0.f;
      asm volatile("" : "+v"(bz[kk]));   // opaque: MFMA can't be folded
    }
#pragma unroll
    for (int nt = 0; nt < NT; ++nt) group(nt, bz);
  } else {
    f16x8 b0[KK], b1[KK];
#pragma unroll
    for (int kk = 0; kk < KK; ++kk) b0[kk] = loadB(0, kk);
#pragma unroll
    for (int nt = 0; nt < NT; nt += 2) {
#pragma unroll
      for (int kk = 0; kk < KK; ++kk) b1[kk] = loadB(nt + 1, kk);
      group(nt, b0);
      if (nt + 2 < NT) {
#pragma unroll
        for (int kk = 0; kk < KK; ++kk) b0[kk] = loadB(nt + 2, kk);
      }
      group(nt + 1, b1);
    }
  }

#pragma unroll
  for (int c0 = 0; c0 < NT * 16; c0 += 64) {
    const int c = c0 + lane;
    if (c < NT * 16) {
      const float v0 = pm[0 * S + c], v1 = pm[1 * S + c];
      const float v2 = pm[2 * S + c], v3 = pm[3 * S + c];
      const float mx = fmaxf(fmaxf(v0, v1), fmaxf(v2, v3));
      outp[c] = (half_t)fmaxf(mx + bias[c], 0.f);
    }
  }
}

template<int V>
__global__ __launch_bounds__(256, 4) void conv_any(
    const int* __restrict__ ids, const float* __restrict__ cemb,
    const half_t* __restrict__ Wp, const half_t* __restrict__ Wp2,
    const float* __restrict__ bias_all, half_t* __restrict__ tout) {
  __shared__ char emb_s[4 * 72 * 48];        // 13824 B
  __shared__ float pmax_s[4 * 4 * 264];      // 16896 B
  const int tid = threadIdx.x, wave = tid >> 6, lane = tid & 63;
  const int tok = blockIdx.x * 4 + wave;
  char* myemb = emb_s + wave * (72 * 48);
  float* pm = pmax_s + wave * (4 * 264);

  for (int r = lane; r < 72; r += 64) {
    f16x8 lo, hi;
#pragma unroll
    for (int q = 0; q < 8; ++q) { lo[q] = (half_t)0.f; hi[q] = (half_t)0.f; }
    if (r < NCHAR) {
      const int id = ids[tok * NCHAR + r];
      const float4 v0 = *(const float4*)&cemb[id * EMB + 0];
      const float4 v1 = *(const float4*)&cemb[id * EMB + 4];
      const float4 v2 = *(const float4*)&cemb[id * EMB + 8];
      const float4 v3 = *(const float4*)&cemb[id * EMB + 12];
      lo[0] = (half_t)v0.x; lo[1] = (half_t)v0.y; lo[2] = (half_t)v0.z; lo[3] = (half_t)v0.w;
      lo[4] = (half_t)v1.x; lo[5] = (half_t)v1.y; lo[6] = (half_t)v1.z; lo[7] = (half_t)v1.w;
      hi[0] = (half_t)v2.x; hi[1] = (half_t)v2.y; hi[2] = (half_t)v2.z; hi[3] = (half_t)v2.w;
      hi[4] = (half_t)v3.x; hi[5] = (half_t)v3.y; hi[6] = (half_t)v3.z; hi[7] = (half_t)v3.w;
    }
    *(f16x8*)(myemb + r * 48) = lo;
    *(f16x8*)(myemb + r * 48 + 16) = hi;
  }
  // no barrier: wave-private tile; same-wave ds ordering via lgkmcnt.

  const half_t* W = (V == 2) ? Wp2 : Wp;
  half_t* outp = tout + (size_t)tok * TF;
  switch (blockIdx.y) {
    case 0:
      conv_worker<V, 4, 1, 2, 50>(myemb, pm, W + 0,    bias_all + 0,   outp + 0,   32, lane);
      conv_worker<V, 4, 1, 2, 49>(myemb, pm, W + 1024, bias_all + 32,  outp + 32,  32, lane);
      conv_worker<V, 3, 2, 4, 48>(myemb, pm, W + 2048, bias_all + 64,  outp + 64,  64, lane);
      conv_worker<V, 3, 2, 8, 47>(myemb, pm, W + 6144, bias_all + 128, outp + 128, 64, lane);
      break;
    case 1:  conv_worker<V, 3, 3, 16, 46>(myemb, pm, W + 14336,  bias_all + 256,  outp + 256,  96,  lane); break;
    case 2:  conv_worker<V, 3, 3, 16, 45>(myemb, pm, W + 38912,  bias_all + 512,  outp + 512,  96,  lane); break;
    case 3:  conv_worker<V, 3, 3, 16, 45>(myemb, pm, W + 63488,  bias_all + 768,  outp + 768,  96,  lane); break;
    case 4:  conv_worker<V, 3, 4, 16, 44>(myemb, pm, W + 88064,  bias_all + 1024, outp + 1024, 128, lane); break;
    case 5:  conv_worker<V, 3, 4, 16, 44>(myemb, pm, W + 120832, bias_all + 1280, outp + 1280, 128, lane); break;
    case 6:  conv_worker<V, 3, 4, 16, 44>(myemb, pm, W + 153600, bias_all + 1536, outp + 1536, 128, lane); break;
    default: conv_worker<V, 3, 4, 16, 44>(myemb, pm, W + 186368, bias_all + 1792, outp + 1792, 128, lane); break;
  }
}

// ------------------------------------------------- transpose + f32->f16 ----
__global__ __launch_bounds__(256) void tcvt_kernel(
    const float* __restrict__ src, half_t* __restrict__ dst, int R, int C) {
  __shared__ half_t tile[64][72];
  const int tid = threadIdx.x;
  const int r0 = blockIdx.y * 64, c0 = blockIdx.x * 64;
  const int rr = tid >> 4, cq = tid & 15;
#pragma unroll
  for (int p = 0; p < 4; ++p) {
    const int r = rr + p * 16;
    const float4 v = *(const float4*)&src[(size_t)(r0 + r) * C + c0 + cq * 4];
    tile[cq * 4 + 0][r] = (half_t)v.x;
    tile[cq * 4 + 1][r] = (half_t)v.y;
    tile[cq * 4 + 2][r] = (half_t)v.z;
    tile[cq * 4 + 3][r] = (half_t)v.w;
  }
  __syncthreads();
#pragma unroll
  for (int p = 0; p < 2; ++p) {
    const int item = p * 256 + tid;
    const int c = item >> 3, ch = item & 7;
    const f16x8 v = *(const f16x8*)&tile[c][ch * 8];
    *(f16x8*)&dst[(size_t)(c0 + c) * R + r0 + ch * 8] = v;
  }
}

// ------------------------------------------------------------- highway ----
__global__ __launch_bounds__(256, 2) void highway_kernel(
    const half_t* __restrict__ tin, const half_t* __restrict__ Wt,
    const float* __restrict__ bv, half_t* __restrict__ tout) {
  __shared__ half_t smA[128 * BK];
  __shared__ half_t smBn[128 * BK];
  __shared__ half_t smBg[128 * BK];
  const int tid = threadIdx.x;
  const int wave = tid >> 6, lane = tid & 63;
  const int l15 = lane & 15, l16 = lane >> 4;
  const int wr = wave >> 1, wc = wave & 1;
  const int m0 = blockIdx.y * 128, n0 = blockIdx.x * 128;

  const char* Ab  = (const char*)tin + (size_t)m0 * (TF * 2);
  const char* Bnb = (const char*)Wt + (size_t)n0 * (TF * 2);
  const char* Bgb = (const char*)Wt + (size_t)(n0 + TF) * (TF * 2);

  f32x4 accn[4][4] = {};
  f32x4 accg[4][4] = {};

  for (int kt = 0; kt < TF / BK; ++kt) {
    if (kt) __syncthreads();
    const int kb0 = kt * (BK * 2);
#pragma unroll
    for (int i = 0; i < 4; ++i) {
      const int o = i * 4096 + tid * 16;
      const int row = o >> 7, kb = o & 127;
      const size_t gsrc = (size_t)row * (TF * 2) + kb0 + kb;
      gl_lds16(Ab + gsrc,  (char*)smA  + i * 4096 + wave * 1024);
      gl_lds16(Bnb + gsrc, (char*)smBn + i * 4096 + wave * 1024);
      gl_lds16(Bgb + gsrc, (char*)smBg + i * 4096 + wave * 1024);
    }
    __syncthreads();
#pragma unroll
    for (int ks = 0; ks < 2; ++ks) {
      f16x8 af[4], bn_[4], bg_[4];
#pragma unroll
      for (int m = 0; m < 4; ++m) {
        const int row = wr * 64 + m * 16 + l15;
        af[m] = *(const f16x8*)((const char*)smA + row * 128 + ks * 64 + l16 * 16);
      }
#pragma unroll
      for (int n = 0; n < 4; ++n) {
        const int row = wc * 64 + n * 16 + l15;
        bn_[n] = *(const f16x8*)((const char*)smBn + row * 128 + ks * 64 + l16 * 16);
        bg_[n] = *(const f16x8*)((const char*)smBg + row * 128 + ks * 64 + l16 * 16);
      }
#pragma unroll
      for (int m = 0; m < 4; ++m)
#pragma unroll
        for (int n = 0; n < 4; ++n) {
          accn[m][n] = __builtin_amdgcn_mfma_f32_16x16x32_f16(af[m], bn_[n], accn[m][n], 0, 0, 0);
          accg[m][n] = __builtin_amdgcn_mfma_f32_16x16x32_f16(af[m], bg_[n], accg[m][n], 0, 0, 0);
        }
    }
  }

#pragma unroll
  for (int n = 0; n < 4; ++n) {
    const int gn = n0 + wc * 64 + n * 16 + l15;
    const float bnl = bv[gn];
    const float bgt = bv[TF + gn];
#pragma unroll
    for (int m = 0; m < 4; ++m) {
#pragma unroll
      for (int j = 0; j < 4; ++j) {
        const int gm = m0 + wr * 64 + m * 16 + l16 * 4 + j;
        const float nl = accn[m][n][j] + bnl;
        const float gt = accg[m][n][j] + bgt;
        const float g = 1.f / (1.f + __expf(-gt));
        const float told = (float)tin[(size_t)gm * TF + gn];
        const float o = g * told + (1.f - g) * fmaxf(nl, 0.f);
        tout[(size_t)gm * TF + gn] = (half_t)o;
      }
    }
  }
}

// ---------------------------------------------------------------- proj ----
__global__ __launch_bounds__(256, 2) void proj_kernel(
    const half_t* __restrict__ tin, const half_t* __restrict__ Wt,
    const float* __restrict__ bv, float* __restrict__ out) {
  __shared__ half_t smA[128 * BK];
  __shared__ half_t smB[128 * BK];
  const int tid = threadIdx.x;
  const int wave = tid >> 6, lane = tid & 63;
  const int l15 = lane & 15, l16 = lane >> 4;
  const int wr = wave >> 1, wc = wave & 1;
  const int m0 = blockIdx.y * 128, n0 = blockIdx.x * 128;

  const char* Ab = (const char*)tin + (size_t)m0 * (TF * 2);
  const char* Bb = (const char*)Wt + (size_t)n0 * (TF * 2);

  f32x4 acc[4][4] = {};

  for (int kt = 0; kt < TF / BK; ++kt) {
    if (kt) __syncthreads();
    const int kb0 = kt * (BK * 2);
#pragma unroll
    for (int i = 0; i < 4; ++i) {
      const int o = i * 4096 + tid * 16;
      const int row = o >> 7, kb = o & 127;
      const size_t gsrc = (size_t)row * (TF * 2) + kb0 + kb;
      gl_lds16(Ab + gsrc, (char*)smA + i * 4096 + wave * 1024);
      gl_lds16(Bb + gsrc, (char*)smB + i * 4096 + wave * 1024);
    }
    __syncthreads();
#pragma unroll
    for (int ks = 0; ks < 2; ++ks) {
      f16x8 af[4], bf[4];
#pragma unroll
      for (int m = 0; m < 4; ++m) {
        const int row = wr * 64 + m * 16 + l15;
        af[m] = *(const f16x8*)((const char*)smA + row * 128 + ks * 64 + l16 * 16);
      }
#pragma unroll
      for (int n = 0; n < 4; ++n) {
        const int row = wc * 64 + n * 16 + l15;
        bf[n] = *(const f16x8*)((const char*)smB + row * 128 + ks * 64 + l16 * 16);
      }
#pragma unroll
      for (int m = 0; m < 4; ++m)
#pragma unroll
        for (int n = 0; n < 4; ++n)
          acc[m][n] = __builtin_amdgcn_mfma_f32_16x16x32_f16(af[m], bf[n], acc[m][n], 0, 0, 0);
    }
  }

#pragma unroll
  for (int n = 0; n < 4; ++n) {
    const int gn = n0 + wc * 64 + n * 16 + l15;
    const float bb = bv[gn];
#pragma unroll
    for (int m = 0; m < 4; ++m) {
#pragma unroll
      for (int j = 0; j < 4; ++j) {
        const int gm = m0 + wr * 64 + m * 16 + l16 * 4 + j;
        out[(size_t)gm * HID + gn] = acc[m][n][j] + bb;
      }
    }
  }
}

// -------------------------------------------------------------- launch ----
extern "C" void kernel_launch(void* const* d_in, const int* in_sizes, int n_in,
                              void* d_out, int out_size, void* d_ws, size_t ws_size,
                              hipStream_t stream) {
  const int*   ids  = (const int*)d_in[0];
  const float* cemb = (const float*)d_in[1];
  const float* cw[7]; const float* cb[7];
  for (int i = 0; i < 7; ++i) {
    cw[i] = (const float*)d_in[2 + 2 * i];
    cb[i] = (const float*)d_in[3 + 2 * i];
  }
  const float* hw_w0  = (const float*)d_in[16];
  const float* hw_b0  = (const float*)d_in[17];
  const float* hw_w1  = (const float*)d_in[18];
  const float* hw_b1  = (const float*)d_in[19];
  const float* proj_w = (const float*)d_in[20];
  const float* proj_b = (const float*)d_in[21];
  float* out = (float*)d_out;

  char* ws = (char*)d_ws;
  half_t* t0h      = (half_t*)(ws);
  half_t* t1h      = (half_t*)(ws + 16777216);
  half_t* wbuf     = (half_t*)(ws + 33554432);   // reused: w0t -> w1t -> pwt
  float*  bias_all = (float*)(ws + 50331648);
  half_t* Wp       = (half_t*)(ws + 50339840);
  half_t* Wp2      = (half_t*)(ws + 50778112);

  wpack_kernel<<<864, 256, 0, stream>>>(
      cw[0], cw[1], cw[2], cw[3], cw[4], cw[5], cw[6],
      cb[0], cb[1], cb[2], cb[3], cb[4], cb[5], cb[6], Wp, bias_all);
  wpack2_kernel<<<856, 256, 0, stream>>>(
      cw[0], cw[1], cw[2], cw[3], cw[4], cw[5], cw[6], Wp2);

  // --- diagnostics (1/4 grid, outputs overwritten by real conv below) ---
  conv_any<0><<<dim3(256, 8), 256, 0, stream>>>(ids, cemb, Wp, Wp2, bias_all, t0h);
  conv_any<1><<<dim3(256, 8), 256, 0, stream>>>(ids, cemb, Wp, Wp2, bias_all, t0h);
  // --- real conv: coalesced B, full grid ---
  conv_any<2><<<dim3(NTOK / 4, 8), 256, 0, stream>>>(ids, cemb, Wp, Wp2, bias_all, t0h);

  tcvt_kernel<<<dim3(4096 / 64, TF / 64), 256, 0, stream>>>(hw_w0, wbuf, TF, 4096);
  highway_kernel<<<dim3(TF / 128, NTOK / 128), 256, 0, stream>>>(t0h, wbuf, hw_b0, t1h);

  tcvt_kernel<<<dim3(4096 / 64, TF / 64), 256, 0, stream>>>(hw_w1, wbuf, TF, 4096);
  highway_kernel<<<dim3(TF / 128, NTOK / 128), 256, 0, stream>>>(t1h, wbuf, hw_b1, t0h);

  tcvt_kernel<<<dim3(HID / 64, TF / 64), 256, 0, stream>>>(proj_w, wbuf, TF, HID);
  proj_kernel<<<dim3(HID / 128, NTOK / 128), 256, 0, stream>>>(t0h, wbuf, proj_b, out);
}

// Round 10
// 473.461 us; speedup vs baseline: 1.0984x; 1.0984x over previous
//
#include <hip/hip_runtime.h>
#include <math.h>

// CharacterBertCharacterCNN — Round 10
// conv: coalesced-B MFMA (R9-verified, 102us). highway/proj: FRAGMENT-MAJOR
// LDS layout — global source pre-permuted per-lane so gl_lds16's linear LDS
// write lands data exactly in fragment read order; ds_read_b128 becomes
// stride-1 conflict-free (R9: 18.9M bank-conflict cycles, 16-way on row
// stride 128B, LDS-bound at 102us/dispatch). Diag dispatches removed.
//
// ws layout (bytes):
//   t0h      @ 0         : 16,777,216
//   t1h      @ 16777216  : 16,777,216
//   wbuf     @ 33554432  : 16,777,216   (w0t, then w1t, then pwt)
//   bias_all @ 50331648  : 8,192
//   Wp2      @ 50339840  : 438,272     (coalesced conv weights)
//   total ~50.8 MB

#define NTOK 4096
#define NCHAR 50
#define EMB 16
#define TF 2048
#define HID 768
#define BK 64       // GEMM k-tile

typedef float f32x4 __attribute__((ext_vector_type(4)));
typedef _Float16 f16x8 __attribute__((ext_vector_type(8)));
typedef _Float16 half_t;

__device__ __forceinline__ void gl_lds16(const void* g, void* l) {
  __builtin_amdgcn_global_load_lds(
      (const __attribute__((address_space(1))) void*)g,
      (__attribute__((address_space(3))) void*)l, 16, 0, 0);
}

// ------------------------------------------------------- weight packing ----
// Coalesced conv-weight layout: per (width, nt, kk) a 512-half block ordered
// [lane][e]: half idx = base + ((nt*KKw + kk)*64 + lane)*8 + e, lane =
// l16*16+l15 -> channel nt*16+l15, k = kk*32 + l16*8 + e (k = j*16+i).
// Width bases (halfs): W1@0 W2@1024 W3@2048 W4@6144 W5@14336 W6@38912
// W7@88064, total 219136. idx 219136..221183: bias_all.
__global__ __launch_bounds__(256) void wpack2_kernel(
    const float* __restrict__ w0, const float* __restrict__ w1,
    const float* __restrict__ w2, const float* __restrict__ w3,
    const float* __restrict__ w4, const float* __restrict__ w5,
    const float* __restrict__ w6,
    const float* __restrict__ b0, const float* __restrict__ b1,
    const float* __restrict__ b2, const float* __restrict__ b3,
    const float* __restrict__ b4, const float* __restrict__ b5,
    const float* __restrict__ b6,
    half_t* __restrict__ Wp2, float* __restrict__ bias_all) {
  const int idx = blockIdx.x * 256 + threadIdx.x;
  if (idx < 219136) {
    int t, w, kpad; const float* src;
    if (idx < 1024)       { t = idx;          w = 1; kpad = 32;  src = w0; }
    else if (idx < 2048)  { t = idx - 1024;   w = 2; kpad = 32;  src = w1; }
    else if (idx < 6144)  { t = idx - 2048;   w = 3; kpad = 64;  src = w2; }
    else if (idx < 14336) { t = idx - 6144;   w = 4; kpad = 64;  src = w3; }
    else if (idx < 38912) { t = idx - 14336;  w = 5; kpad = 96;  src = w4; }
    else if (idx < 88064) { t = idx - 38912;  w = 6; kpad = 96;  src = w5; }
    else                  { t = idx - 88064;  w = 7; kpad = 128; src = w6; }
    const int e = t & 7, lane = (t >> 3) & 63, blk = t >> 9;
    const int KKw = kpad >> 5;
    const int kk = blk % KKw, nt = blk / KKw;
    const int c = nt * 16 + (lane & 15);
    const int k = kk * 32 + (lane >> 4) * 8 + e;
    const int j = k >> 4, i = k & 15;
    Wp2[idx] = (half_t)((j < w) ? src[(c * EMB + i) * w + j] : 0.f);
  } else if (idx < 219136 + 2048) {
    const int c = idx - 219136;
    float v;
    if (c < 32)        v = b0[c];
    else if (c < 64)   v = b1[c - 32];
    else if (c < 128)  v = b2[c - 64];
    else if (c < 256)  v = b3[c - 128];
    else if (c < 512)  v = b4[c - 256];
    else if (c < 1024) v = b5[c - 512];
    else               v = b6[c - 1024];
    bias_all[c] = v;
  }
}

// ---------------------------------------------------------------- conv ----
// Per wave: one token. emb tile f16 in LDS (72 rows x 48B, rows >=50 zero).
// A-frags loaded once, pinned. B from Wp2 coalesced blocks, double-buffered.
// Epilogue: compile-time-masked tree max -> pm -> batched final reduce.

template<int MT, int KK, int NT, int L>
__device__ __forceinline__ void conv_worker(
    const char* myemb, float* pm,
    const half_t* __restrict__ W, const float* __restrict__ bias,
    half_t* __restrict__ outp, int lane) {
  constexpr int S = NT * 16 + 8;
  const int l15 = lane & 15, l16 = lane >> 4;

  f16x8 a[MT][KK];
#pragma unroll
  for (int m = 0; m < MT; ++m)
#pragma unroll
    for (int kk = 0; kk < KK; ++kk) {
      const int row = m * 16 + l15 + 2 * kk + (l16 >> 1);
      a[m][kk] = *(const f16x8*)(myemb + row * 48 + (l16 & 1) * 16);
    }
#pragma unroll
  for (int m = 0; m < MT; ++m)
#pragma unroll
    for (int kk = 0; kk < KK; ++kk)
      asm volatile("" : "+v"(a[m][kk]));

  const half_t* bpc = W + (size_t)lane * 8;
  auto loadB = [&](int nt, int kk) -> f16x8 {
    return *(const f16x8*)(bpc + (((size_t)nt * KK + kk) << 9));
  };

  auto group = [&](int nt, const f16x8 (&b)[KK]) {
    f32x4 acc[MT];
#pragma unroll
    for (int m = 0; m < MT; ++m) acc[m] = (f32x4){0.f, 0.f, 0.f, 0.f};
#pragma unroll
    for (int kk = 0; kk < KK; ++kk)
#pragma unroll
      for (int m = 0; m < MT; ++m)
        acc[m] = __builtin_amdgcn_mfma_f32_16x16x32_f16(a[m][kk], b[kk], acc[m], 0, 0, 0);
    float t[MT * 4];
#pragma unroll
    for (int m = 0; m < MT; ++m)
#pragma unroll
      for (int j = 0; j < 4; ++j) {
        const int pos = m * 16 + l16 * 4 + j;
        if ((m * 16 + 15) < L)
          t[m * 4 + j] = acc[m][j];
        else
          t[m * 4 + j] = (pos < L) ? acc[m][j] : -1e30f;
      }
#pragma unroll
    for (int s = 1; s < MT * 4; s *= 2)
#pragma unroll
      for (int i = 0; i + s < MT * 4; i += 2 * s)
        t[i] = fmaxf(t[i], t[i + s]);
    pm[l16 * S + nt * 16 + l15] = t[0];
  };

  f16x8 b0[KK], b1[KK];
#pragma unroll
  for (int kk = 0; kk < KK; ++kk) b0[kk] = loadB(0, kk);
#pragma unroll
  for (int nt = 0; nt < NT; nt += 2) {
#pragma unroll
    for (int kk = 0; kk < KK; ++kk) b1[kk] = loadB(nt + 1, kk);
    group(nt, b0);
    if (nt + 2 < NT) {
#pragma unroll
      for (int kk = 0; kk < KK; ++kk) b0[kk] = loadB(nt + 2, kk);
    }
    group(nt + 1, b1);
  }

#pragma unroll
  for (int c0 = 0; c0 < NT * 16; c0 += 64) {
    const int c = c0 + lane;
    if (c < NT * 16) {
      const float v0 = pm[0 * S + c], v1 = pm[1 * S + c];
      const float v2 = pm[2 * S + c], v3 = pm[3 * S + c];
      const float mx = fmaxf(fmaxf(v0, v1), fmaxf(v2, v3));
      outp[c] = (half_t)fmaxf(mx + bias[c], 0.f);
    }
  }
}

// 8 balanced slots (MFMAs/token): 0:{W1,W2,W3,W4}=88  1:{W5}=144
// 2,3:{W6 halves}=144  4-7:{W7 quarters}=192
__global__ __launch_bounds__(256, 4) void conv_kernel(
    const int* __restrict__ ids, const float* __restrict__ cemb,
    const half_t* __restrict__ Wp2, const float* __restrict__ bias_all,
    half_t* __restrict__ tout) {
  __shared__ char emb_s[4 * 72 * 48];        // 13824 B
  __shared__ float pmax_s[4 * 4 * 264];      // 16896 B
  const int tid = threadIdx.x, wave = tid >> 6, lane = tid & 63;
  const int tok = blockIdx.x * 4 + wave;
  char* myemb = emb_s + wave * (72 * 48);
  float* pm = pmax_s + wave * (4 * 264);

  for (int r = lane; r < 72; r += 64) {
    f16x8 lo, hi;
#pragma unroll
    for (int q = 0; q < 8; ++q) { lo[q] = (half_t)0.f; hi[q] = (half_t)0.f; }
    if (r < NCHAR) {
      const int id = ids[tok * NCHAR + r];
      const float4 v0 = *(const float4*)&cemb[id * EMB + 0];
      const float4 v1 = *(const float4*)&cemb[id * EMB + 4];
      const float4 v2 = *(const float4*)&cemb[id * EMB + 8];
      const float4 v3 = *(const float4*)&cemb[id * EMB + 12];
      lo[0] = (half_t)v0.x; lo[1] = (half_t)v0.y; lo[2] = (half_t)v0.z; lo[3] = (half_t)v0.w;
      lo[4] = (half_t)v1.x; lo[5] = (half_t)v1.y; lo[6] = (half_t)v1.z; lo[7] = (half_t)v1.w;
      hi[0] = (half_t)v2.x; hi[1] = (half_t)v2.y; hi[2] = (half_t)v2.z; hi[3] = (half_t)v2.w;
      hi[4] = (half_t)v3.x; hi[5] = (half_t)v3.y; hi[6] = (half_t)v3.z; hi[7] = (half_t)v3.w;
    }
    *(f16x8*)(myemb + r * 48) = lo;
    *(f16x8*)(myemb + r * 48 + 16) = hi;
  }
  // no barrier: wave-private tile; same-wave ds ordering via lgkmcnt.

  half_t* outp = tout + (size_t)tok * TF;
  switch (blockIdx.y) {
    case 0:
      conv_worker<4, 1, 2, 50>(myemb, pm, Wp2 + 0,    bias_all + 0,   outp + 0,   lane);
      conv_worker<4, 1, 2, 49>(myemb, pm, Wp2 + 1024, bias_all + 32,  outp + 32,  lane);
      conv_worker<3, 2, 4, 48>(myemb, pm, Wp2 + 2048, bias_all + 64,  outp + 64,  lane);
      conv_worker<3, 2, 8, 47>(myemb, pm, Wp2 + 6144, bias_all + 128, outp + 128, lane);
      break;
    case 1:  conv_worker<3, 3, 16, 46>(myemb, pm, Wp2 + 14336,  bias_all + 256,  outp + 256,  lane); break;
    case 2:  conv_worker<3, 3, 16, 45>(myemb, pm, Wp2 + 38912,  bias_all + 512,  outp + 512,  lane); break;
    case 3:  conv_worker<3, 3, 16, 45>(myemb, pm, Wp2 + 63488,  bias_all + 768,  outp + 768,  lane); break;
    case 4:  conv_worker<3, 4, 16, 44>(myemb, pm, Wp2 + 88064,  bias_all + 1024, outp + 1024, lane); break;
    case 5:  conv_worker<3, 4, 16, 44>(myemb, pm, Wp2 + 120832, bias_all + 1280, outp + 1280, lane); break;
    case 6:  conv_worker<3, 4, 16, 44>(myemb, pm, Wp2 + 153600, bias_all + 1536, outp + 1536, lane); break;
    default: conv_worker<3, 4, 16, 44>(myemb, pm, Wp2 + 186368, bias_all + 1792, outp + 1792, lane); break;
  }
}

// ------------------------------------------------- transpose + f32->f16 ----
__global__ __launch_bounds__(256) void tcvt_kernel(
    const float* __restrict__ src, half_t* __restrict__ dst, int R, int C) {
  __shared__ half_t tile[64][72];
  const int tid = threadIdx.x;
  const int r0 = blockIdx.y * 64, c0 = blockIdx.x * 64;
  const int rr = tid >> 4, cq = tid & 15;
#pragma unroll
  for (int p = 0; p < 4; ++p) {
    const int r = rr + p * 16;
    const float4 v = *(const float4*)&src[(size_t)(r0 + r) * C + c0 + cq * 4];
    tile[cq * 4 + 0][r] = (half_t)v.x;
    tile[cq * 4 + 1][r] = (half_t)v.y;
    tile[cq * 4 + 2][r] = (half_t)v.z;
    tile[cq * 4 + 3][r] = (half_t)v.w;
  }
  __syncthreads();
#pragma unroll
  for (int p = 0; p < 2; ++p) {
    const int item = p * 256 + tid;
    const int c = item >> 3, ch = item & 7;
    const f16x8 v = *(const f16x8*)&tile[c][ch * 8];
    *(f16x8*)&dst[(size_t)(c0 + c) * R + r0 + ch * 8] = v;
  }
}

// ------------------------------------------------------------- highway ----
// FRAGMENT-MAJOR LDS: granule g = (group*2 + ks)*64 + lane (16B each) holds
// A[row=(group)*16 + (lane&15)][kbytes = ks*64 + (lane>>4)*16] of the k-slice.
// Staging: sub = i*4+wave (wave-uniform) = group*2+ks; per-lane global addr
// permuted to match; LDS dest stays linear (rule: swizzle source, not dest).
// Reads are stride-1 (lane*16B) -> conflict-free ds_read_b128.
__global__ __launch_bounds__(256, 2) void highway_kernel(
    const half_t* __restrict__ tin, const half_t* __restrict__ Wt,
    const float* __restrict__ bv, half_t* __restrict__ tout) {
  __shared__ half_t smA[128 * BK];
  __shared__ half_t smBn[128 * BK];
  __shared__ half_t smBg[128 * BK];
  const int tid = threadIdx.x;
  const int wave = tid >> 6, lane = tid & 63;
  const int l15 = lane & 15, l16 = lane >> 4;
  const int wr = wave >> 1, wc = wave & 1;
  const int m0 = blockIdx.y * 128, n0 = blockIdx.x * 128;

  const char* Ab  = (const char*)tin + (size_t)m0 * (TF * 2);
  const char* Bnb = (const char*)Wt + (size_t)n0 * (TF * 2);
  const char* Bgb = (const char*)Wt + (size_t)(n0 + TF) * (TF * 2);

  f32x4 accn[4][4] = {};
  f32x4 accg[4][4] = {};

  for (int kt = 0; kt < TF / BK; ++kt) {
    if (kt) __syncthreads();
    const int kb0 = kt * (BK * 2);
#pragma unroll
    for (int i = 0; i < 4; ++i) {
      const int sub = i * 4 + wave;               // wave-uniform: group*2+ks
      const int row = (sub >> 1) * 16 + l15;
      const int kcb = (sub & 1) * 64 + l16 * 16;  // byte col within 128B slice
      const size_t gsrc = (size_t)row * (TF * 2) + kb0 + kcb;
      gl_lds16(Ab + gsrc,  (char*)smA  + i * 4096 + wave * 1024);
      gl_lds16(Bnb + gsrc, (char*)smBn + i * 4096 + wave * 1024);
      gl_lds16(Bgb + gsrc, (char*)smBg + i * 4096 + wave * 1024);
    }
    __syncthreads();
#pragma unroll
    for (int ks = 0; ks < 2; ++ks) {
      f16x8 af[4], bn_[4], bg_[4];
#pragma unroll
      for (int m = 0; m < 4; ++m)
        af[m] = *(const f16x8*)((const char*)smA +
                 ((((wr * 4 + m) * 2 + ks) * 64 + lane) << 4));
#pragma unroll
      for (int n = 0; n < 4; ++n) {
        const int go = (((wc * 4 + n) * 2 + ks) * 64 + lane) << 4;
        bn_[n] = *(const f16x8*)((const char*)smBn + go);
        bg_[n] = *(const f16x8*)((const char*)smBg + go);
      }
#pragma unroll
      for (int m = 0; m < 4; ++m)
#pragma unroll
        for (int n = 0; n < 4; ++n) {
          accn[m][n] = __builtin_amdgcn_mfma_f32_16x16x32_f16(af[m], bn_[n], accn[m][n], 0, 0, 0);
          accg[m][n] = __builtin_amdgcn_mfma_f32_16x16x32_f16(af[m], bg_[n], accg[m][n], 0, 0, 0);
        }
    }
  }

#pragma unroll
  for (int n = 0; n < 4; ++n) {
    const int gn = n0 + wc * 64 + n * 16 + l15;
    const float bnl = bv[gn];
    const float bgt = bv[TF + gn];
#pragma unroll
    for (int m = 0; m < 4; ++m) {
#pragma unroll
      for (int j = 0; j < 4; ++j) {
        const int gm = m0 + wr * 64 + m * 16 + l16 * 4 + j;
        const float nl = accn[m][n][j] + bnl;
        const float gt = accg[m][n][j] + bgt;
        const float g = 1.f / (1.f + __expf(-gt));
        const float told = (float)tin[(size_t)gm * TF + gn];
        const float o = g * told + (1.f - g) * fmaxf(nl, 0.f);
        tout[(size_t)gm * TF + gn] = (half_t)o;
      }
    }
  }
}

// ---------------------------------------------------------------- proj ----
__global__ __launch_bounds__(256, 2) void proj_kernel(
    const half_t* __restrict__ tin, const half_t* __restrict__ Wt,
    const float* __restrict__ bv, float* __restrict__ out) {
  __shared__ half_t smA[128 * BK];
  __shared__ half_t smB[128 * BK];
  const int tid = threadIdx.x;
  const int wave = tid >> 6, lane = tid & 63;
  const int l15 = lane & 15, l16 = lane >> 4;
  const int wr = wave >> 1, wc = wave & 1;
  const int m0 = blockIdx.y * 128, n0 = blockIdx.x * 128;

  const char* Ab = (const char*)tin + (size_t)m0 * (TF * 2);
  const char* Bb = (const char*)Wt + (size_t)n0 * (TF * 2);

  f32x4 acc[4][4] = {};

  for (int kt = 0; kt < TF / BK; ++kt) {
    if (kt) __syncthreads();
    const int kb0 = kt * (BK * 2);
#pragma unroll
    for (int i = 0; i < 4; ++i) {
      const int sub = i * 4 + wave;
      const int row = (sub >> 1) * 16 + l15;
      const int kcb = (sub & 1) * 64 + l16 * 16;
      const size_t gsrc = (size_t)row * (TF * 2) + kb0 + kcb;
      gl_lds16(Ab + gsrc, (char*)smA + i * 4096 + wave * 1024);
      gl_lds16(Bb + gsrc, (char*)smB + i * 4096 + wave * 1024);
    }
    __syncthreads();
#pragma unroll
    for (int ks = 0; ks < 2; ++ks) {
      f16x8 af[4], bf[4];
#pragma unroll
      for (int m = 0; m < 4; ++m)
        af[m] = *(const f16x8*)((const char*)smA +
                 ((((wr * 4 + m) * 2 + ks) * 64 + lane) << 4));
#pragma unroll
      for (int n = 0; n < 4; ++n)
        bf[n] = *(const f16x8*)((const char*)smB +
                 ((((wc * 4 + n) * 2 + ks) * 64 + lane) << 4));
#pragma unroll
      for (int m = 0; m < 4; ++m)
#pragma unroll
        for (int n = 0; n < 4; ++n)
          acc[m][n] = __builtin_amdgcn_mfma_f32_16x16x32_f16(af[m], bf[n], acc[m][n], 0, 0, 0);
    }
  }

#pragma unroll
  for (int n = 0; n < 4; ++n) {
    const int gn = n0 + wc * 64 + n * 16 + l15;
    const float bb = bv[gn];
#pragma unroll
    for (int m = 0; m < 4; ++m) {
#pragma unroll
      for (int j = 0; j < 4; ++j) {
        const int gm = m0 + wr * 64 + m * 16 + l16 * 4 + j;
        out[(size_t)gm * HID + gn] = acc[m][n][j] + bb;
      }
    }
  }
}

// -------------------------------------------------------------- launch ----
extern "C" void kernel_launch(void* const* d_in, const int* in_sizes, int n_in,
                              void* d_out, int out_size, void* d_ws, size_t ws_size,
                              hipStream_t stream) {
  const int*   ids  = (const int*)d_in[0];
  const float* cemb = (const float*)d_in[1];
  const float* cw[7]; const float* cb[7];
  for (int i = 0; i < 7; ++i) {
    cw[i] = (const float*)d_in[2 + 2 * i];
    cb[i] = (const float*)d_in[3 + 2 * i];
  }
  const float* hw_w0  = (const float*)d_in[16];
  const float* hw_b0  = (const float*)d_in[17];
  const float* hw_w1  = (const float*)d_in[18];
  const float* hw_b1  = (const float*)d_in[19];
  const float* proj_w = (const float*)d_in[20];
  const float* proj_b = (const float*)d_in[21];
  float* out = (float*)d_out;

  char* ws = (char*)d_ws;
  half_t* t0h      = (half_t*)(ws);
  half_t* t1h      = (half_t*)(ws + 16777216);
  half_t* wbuf     = (half_t*)(ws + 33554432);   // reused: w0t -> w1t -> pwt
  float*  bias_all = (float*)(ws + 50331648);
  half_t* Wp2      = (half_t*)(ws + 50339840);

  wpack2_kernel<<<864, 256, 0, stream>>>(
      cw[0], cw[1], cw[2], cw[3], cw[4], cw[5], cw[6],
      cb[0], cb[1], cb[2], cb[3], cb[4], cb[5], cb[6], Wp2, bias_all);

  conv_kernel<<<dim3(NTOK / 4, 8), 256, 0, stream>>>(ids, cemb, Wp2, bias_all, t0h);

  tcvt_kernel<<<dim3(4096 / 64, TF / 64), 256, 0, stream>>>(hw_w0, wbuf, TF, 4096);
  highway_kernel<<<dim3(TF / 128, NTOK / 128), 256, 0, stream>>>(t0h, wbuf, hw_b0, t1h);

  tcvt_kernel<<<dim3(4096 / 64, TF / 64), 256, 0, stream>>>(hw_w1, wbuf, TF, 4096);
  highway_kernel<<<dim3(TF / 128, NTOK / 128), 256, 0, stream>>>(t1h, wbuf, hw_b1, t0h);

  tcvt_kernel<<<dim3(HID / 64, TF / 64), 256, 0, stream>>>(proj_w, wbuf, TF, HID);
  proj_kernel<<<dim3(HID / 128, NTOK / 128), 256, 0, stream>>>(t0h, wbuf, proj_b, out);
}